// Round 20
// baseline (307.965 us; speedup 1.0000x reference)
//
#include <hip/hip_runtime.h>

typedef __attribute__((ext_vector_type(4))) float f4;

__device__ inline float dot4(f4 a, f4 b) { return a.x*b.x + a.y*b.y + a.z*b.z + a.w*b.w; }

// Design-matrix cell never tested: R1's thin row layout (12 VGPR/buffer, no
// MFMA fragments) + R15's straight-line depth-2 single-basic-block pipeline.
// Lane (r,c): r=lane>>4 row-in-quad, c=lane&15 f4-chunk. Each iteration
// handles 4 rows with 4 VMEM loads (1 nodes dword + 3 dwordx4, all
// 256B-coalesced segments). Depth-2 = 24 feature regs -> total ~75-90 VGPR
// -> 6-8 waves/SIMD = 3-4x the gather concurrency of the MFMA structure
// (which was pinned at 2 waves/SIMD by its 96-reg buffers). Matvec in f32
// VALU via wave-private LDS broadcast (R1-proven); VALU total ~18us << dur.
// 8192 blocks = many wave generations (R19: generation smoothing > prologue
// amortization). Zero barriers; plain stores; nt-loads on streams.
__global__ __launch_bounds__(256, 4)   // cap 128: guarantees >=4 waves/SIMD, no squeeze (~80 needed)
void encoder_rows(const int* __restrict__ nodes,
                  const float* __restrict__ W,    // [V,64]
                  const float* __restrict__ L1,   // [B,64]
                  const float* __restrict__ L2,   // [B,64]
                  const float* __restrict__ AW,   // [128]
                  const float* __restrict__ ABv,  // [1]
                  const float* __restrict__ BW,   // [128]
                  const float* __restrict__ BBv,  // [1]
                  const float* __restrict__ GW,   // [64,64] row-major
                  const float* __restrict__ GB,   // [64]
                  float* __restrict__ out,        // [B,64]
                  int nrows)
{
    const int lane = threadIdx.x & 63;
    const int wid  = threadIdx.x >> 6;
    const int r    = lane >> 4;    // row within quad (load/gate layout)
    const int c    = lane & 15;    // f4 chunk within row

    __shared__ f4 cbuf[4][4][16];  // [wave][row][chunk], wave-private, 4 KB

    const unsigned nQuads = (unsigned)nrows >> 2;            // 131072
    const unsigned stride = (unsigned)gridDim.x * 4u;        // 32768 waves

    const float ab = ABv[0], bb = BBv[0];
    // per-lane gate weights in chunk layout (hoisted: 4 f4 = 16 regs)
    const f4 awS = reinterpret_cast<const f4*>(AW)[c];
    const f4 awL = reinterpret_cast<const f4*>(AW)[16 + c];
    const f4 bwS = reinterpret_cast<const f4*>(BW)[c];
    const f4 bwL = reinterpret_cast<const f4*>(BW)[16 + c];
    const float gb = GB[lane];          // matvec layout: lane = output dim d
    const f4* gwp = reinterpret_cast<const f4*>(GW + (unsigned)lane * 64u);

    auto loadQ = [&](unsigned q, f4& w, f4& x, f4& y) {
        const int nidx = nodes[q * 4u + (unsigned)r];
        w = reinterpret_cast<const f4*>(W + (unsigned)nidx * 64u)[c];
        const unsigned row = q * 4u + (unsigned)r;
        x = __builtin_nontemporal_load(reinterpret_cast<const f4*>(L1 + (size_t)row * 64u) + c);
        y = __builtin_nontemporal_load(reinterpret_cast<const f4*>(L2 + (size_t)row * 64u) + c);
    };

    auto computeQ = [&](f4 w, f4 x, f4 y, unsigned q) {
        // gates: partial dot in chunk layout, reduce across the 16-lane row group
        float pa = dot4(w, awS) + dot4(x, awL);
        float pb = dot4(w, bwS) + dot4(y, bwL);
        pa += __shfl_xor(pa, 1); pa += __shfl_xor(pa, 2);
        pa += __shfl_xor(pa, 4); pa += __shfl_xor(pa, 8);
        pb += __shfl_xor(pb, 1); pb += __shfl_xor(pb, 2);
        pb += __shfl_xor(pb, 4); pb += __shfl_xor(pb, 8);
        const float alpha = pa + ab;
        const float beta  = pb + bb;

        // combined in chunk layout -> wave-private LDS (no barrier; lgkmcnt only)
        cbuf[wid][r][c] = w + alpha * x + beta * y;

        // matvec in d layout: lane d, acc[r2] = GB[d] + sum_k GW[d][k]*c[r2][k]
        float acc0 = gb, acc1 = gb, acc2 = gb, acc3 = gb;
#pragma unroll
        for (int k4 = 0; k4 < 16; ++k4) {
            const f4 g4 = gwp[k4];                      // L1-resident (16 KB)
            const f4 c0 = cbuf[wid][0][k4];             // broadcast reads
            const f4 c1 = cbuf[wid][1][k4];
            const f4 c2 = cbuf[wid][2][k4];
            const f4 c3 = cbuf[wid][3][k4];
            acc0 += dot4(g4, c0);
            acc1 += dot4(g4, c1);
            acc2 += dot4(g4, c2);
            acc3 += dot4(g4, c3);
        }
        const unsigned row0 = q * 4u;
        out[(row0 + 0u) * 64u + (unsigned)lane] = acc0;
        out[(row0 + 1u) * 64u + (unsigned)lane] = acc1;
        out[(row0 + 2u) * 64u + (unsigned)lane] = acc2;
        out[(row0 + 3u) * 64u + (unsigned)lane] = acc3;
    };

    const unsigned q0 = (unsigned)blockIdx.x * 4u + (unsigned)wid;

    if (4u * stride == nQuads && q0 + 3u * stride < nQuads) {
        // ---- fast path (bench shape): 4 quads/wave, ONE basic block, depth-2 ----
        const unsigned q1 = q0 + stride, q2 = q1 + stride, q3 = q2 + stride;
        f4 wA, xA, yA, wB, xB, yB;
        loadQ(q0, wA, xA, yA);          // 4 loads in flight
        loadQ(q1, wB, xB, yB);          // 8 in flight
        computeQ(wA, xA, yA, q0);       // waits only q0's loads
        loadQ(q2, wA, xA, yA);          // refill
        computeQ(wB, xB, yB, q1);
        loadQ(q3, wB, xB, yB);          // refill
        computeQ(wA, xA, yA, q2);
        computeQ(wB, xB, yB, q3);
    } else {
        // ---- generic fallback (not taken in bench) ----
        for (unsigned q = q0; q < nQuads; q += stride) {
            f4 w, x, y;
            loadQ(q, w, x, y);
            computeQ(w, x, y, q);
        }
    }
}

extern "C" void kernel_launch(void* const* d_in, const int* in_sizes, int n_in,
                              void* d_out, int out_size, void* d_ws, size_t ws_size,
                              hipStream_t stream) {
    const int*   nodes = (const int*)  d_in[0];
    const float* W     = (const float*)d_in[1];
    const float* L1    = (const float*)d_in[2];
    const float* L2    = (const float*)d_in[3];
    const float* AW    = (const float*)d_in[4];
    const float* AB    = (const float*)d_in[5];
    const float* BW    = (const float*)d_in[6];
    const float* BB    = (const float*)d_in[7];
    const float* GW    = (const float*)d_in[8];
    const float* GB    = (const float*)d_in[9];
    float* out = (float*)d_out;
    const int nrows = in_sizes[0];  // B = 524288

    // 8192 blocks x 4 waves = 32768 persistent waves, exactly 4 quads each;
    // many wave generations per CU -> gather-variance smoothing
    hipLaunchKernelGGL(encoder_rows, dim3(8192), dim3(256), 0, stream,
                       nodes, W, L1, L2, AW, AB, BW, BB, GW, GB, out, nrows);
}

// Round 21
// 107.768 us; speedup vs baseline: 2.8577x; 2.8577x over previous
//
#include <hip/hip_runtime.h>

typedef __attribute__((ext_vector_type(8))) short short8;   // 8 bf16 in 4 VGPRs
typedef __attribute__((ext_vector_type(4))) float f32x4;    // MFMA accumulator
typedef __attribute__((ext_vector_type(4))) float f4;       // float4 as ext_vector

__device__ inline float dot4(f4 a, f4 b) { return a.x*b.x + a.y*b.y + a.z*b.z + a.w*b.w; }
__device__ inline f4 comb4(f4 s, float al, f4 x, float be, f4 y) { return s + al*x + be*y; }

__device__ inline short bf16rne(float x) {   // f32 -> bf16 bits, round-nearest-even
    unsigned u = __float_as_uint(x);
    u += 0x7FFFu + ((u >> 16) & 1u);
    return (short)(u >> 16);
}
__device__ inline short8 pack_bf16(f4 a, f4 b) {
    short8 r;
    r[0] = bf16rne(a.x); r[1] = bf16rne(a.y); r[2] = bf16rne(a.z); r[3] = bf16rne(a.w);
    r[4] = bf16rne(b.x); r[5] = bf16rne(b.y); r[6] = bf16rne(b.z); r[7] = bf16rne(b.w);
    return r;
}

struct Feats { f4 w[4]; f4 x[4]; f4 y[4]; };   // self / l1 / l2 fragments (48 VGPRs)

// FINAL: R15 verbatim — best measured configuration (107.7 us).
// Depth-2 straight-line pipeline, ONE basic block steady state (branchy
// loops collapse the waitcnt pipeline: R12 133 -> R15 107.7). MFMA matvec
// with per-wave cached GW B-fragments; (256,1) no-squeeze cap — every
// squeezed-tier attempt (R2/R4/R12/R14/R18/R20) spilled (WRITE inflation
// signature). nt-loads on streams (FETCH 277->198 MB), plain stores
// (WRITE = 131 MB exact). Depth-3 refuted (R16 compiler re-sinks, R17
// pinning blocks interleave); 8-iter amortization refuted (R19, loses
// generation smoothing); thin-row layout refuted (R20, matvec transients
// spill). Residual vs the 52 us stream-roofline is the random-gather
// service rate (~1.25 TB/s for 256B rows from the 256MB L3-resident
// table) — not addressable from kernel structure on this chip.
__global__ __launch_bounds__(256, 1)
void encoder_mfma(const int* __restrict__ nodes,
                  const float* __restrict__ W,    // [V,64]
                  const float* __restrict__ L1,   // [B,64]
                  const float* __restrict__ L2,   // [B,64]
                  const float* __restrict__ AW,   // [128]
                  const float* __restrict__ ABv,  // [1]
                  const float* __restrict__ BW,   // [128]
                  const float* __restrict__ BBv,  // [1]
                  const float* __restrict__ GW,   // [64,64] row-major
                  const float* __restrict__ GB,   // [64]
                  float* __restrict__ out,        // [B,64]
                  int nrows)
{
    const int lane = threadIdx.x & 63;
    const int wid  = threadIdx.x >> 6;
    const int m    = lane & 15;   // A row / C col within tile
    const int g    = lane >> 4;   // k-group

    // float4 indices of this lane's k-chunks: k = 8g..8g+7 and 32+8g..32+8g+7
    const int i0 = 2 * g, i1 = 2 * g + 1, i2 = 8 + 2 * g, i3 = 9 + 2 * g;

    const unsigned nGroups = (unsigned)nrows >> 4;           // 32768
    const unsigned stride  = (unsigned)gridDim.x * 4u;       // 8192 waves

    // ---- per-wave invariants: GW^T B-fragments + biases (amortized) ----
    short8 gB0[4], gB1[4];
    float  gbv[4];
#pragma unroll
    for (int t = 0; t < 4; ++t) {
        const int n = t * 16 + m;
        const f4* Gp = reinterpret_cast<const f4*>(GW + (unsigned)n * 64u);
        gB0[t] = pack_bf16(Gp[i0], Gp[i1]);
        gB1[t] = pack_bf16(Gp[i2], Gp[i3]);
        gbv[t] = GB[n];
    }
    const float ab = ABv[0], bb = BBv[0];
    const f4* AWp = reinterpret_cast<const f4*>(AW);
    const f4* BWp = reinterpret_cast<const f4*>(BW);

    auto load_feats = [&](int nidx, unsigned grpL) -> Feats {
        Feats F;
        const unsigned row = grpL * 16u + (unsigned)m;
        const f4* Wp  = reinterpret_cast<const f4*>(W + (unsigned)nidx * 64u);
        const f4* L1p = reinterpret_cast<const f4*>(L1 + (size_t)row * 64u);
        const f4* L2p = reinterpret_cast<const f4*>(L2 + (size_t)row * 64u);
        F.w[0] = Wp[i0]; F.w[1] = Wp[i1]; F.w[2] = Wp[i2]; F.w[3] = Wp[i3];
        F.x[0] = __builtin_nontemporal_load(L1p + i0);
        F.x[1] = __builtin_nontemporal_load(L1p + i1);
        F.x[2] = __builtin_nontemporal_load(L1p + i2);
        F.x[3] = __builtin_nontemporal_load(L1p + i3);
        F.y[0] = __builtin_nontemporal_load(L2p + i0);
        F.y[1] = __builtin_nontemporal_load(L2p + i1);
        F.y[2] = __builtin_nontemporal_load(L2p + i2);
        F.y[3] = __builtin_nontemporal_load(L2p + i3);
        return F;
    };

    auto compute_store = [&](const Feats& F, unsigned grpC) {
        const unsigned row0 = grpC * 16u;
        // gates in f32
        float pa = dot4(F.w[0], AWp[i0]) + dot4(F.w[1], AWp[i1])
                 + dot4(F.w[2], AWp[i2]) + dot4(F.w[3], AWp[i3])
                 + dot4(F.x[0], AWp[16 + i0]) + dot4(F.x[1], AWp[16 + i1])
                 + dot4(F.x[2], AWp[16 + i2]) + dot4(F.x[3], AWp[16 + i3]);
        float pb = dot4(F.w[0], BWp[i0]) + dot4(F.w[1], BWp[i1])
                 + dot4(F.w[2], BWp[i2]) + dot4(F.w[3], BWp[i3])
                 + dot4(F.y[0], BWp[16 + i0]) + dot4(F.y[1], BWp[16 + i1])
                 + dot4(F.y[2], BWp[16 + i2]) + dot4(F.y[3], BWp[16 + i3]);
        // row m lives on lanes {m, m+16, m+32, m+48}
        pa += __shfl_xor(pa, 16); pa += __shfl_xor(pa, 32);
        pb += __shfl_xor(pb, 16); pb += __shfl_xor(pb, 32);
        const float alpha = pa + ab;
        const float beta  = pb + bb;

        const short8 a0 = pack_bf16(comb4(F.w[0], alpha, F.x[0], beta, F.y[0]),
                                    comb4(F.w[1], alpha, F.x[1], beta, F.y[1]));
        const short8 a1 = pack_bf16(comb4(F.w[2], alpha, F.x[2], beta, F.y[2]),
                                    comb4(F.w[3], alpha, F.x[3], beta, F.y[3]));

        f32x4 acc[4];
#pragma unroll
        for (int t = 0; t < 4; ++t) {
            acc[t][0] = gbv[t]; acc[t][1] = gbv[t]; acc[t][2] = gbv[t]; acc[t][3] = gbv[t];
            acc[t] = __builtin_amdgcn_mfma_f32_16x16x32_bf16(a0, gB0[t], acc[t], 0, 0, 0);
            acc[t] = __builtin_amdgcn_mfma_f32_16x16x32_bf16(a1, gB1[t], acc[t], 0, 0, 0);
        }
        // C layout col=lane&15, row=4g+reg (m89-verified); plain stores (WRITE=131 exact)
#pragma unroll
        for (int t = 0; t < 4; ++t) {
#pragma unroll
            for (int r = 0; r < 4; ++r) {
                out[(row0 + 4u * (unsigned)g + r) * 64u + (unsigned)(t * 16 + m)] = acc[t][r];
            }
        }
    };

    const unsigned grp0 = (unsigned)blockIdx.x * 4u + (unsigned)wid;

    if (grp0 + 3u * stride < nGroups && 4u * stride == nGroups) {
        // ---- fast path (bench shape): exactly 4 groups/wave, ONE basic block ----
        const unsigned g1 = grp0 + stride, g2 = g1 + stride, g3 = g2 + stride;
        const int nv0 = nodes[grp0 * 16u + (unsigned)m];
        const int nv1 = nodes[g1   * 16u + (unsigned)m];
        const int nv2 = nodes[g2   * 16u + (unsigned)m];
        const int nv3 = nodes[g3   * 16u + (unsigned)m];

        Feats A = load_feats(nv0, grp0);     // 12 loads in flight
        Feats B = load_feats(nv1, g1);       // 24 in flight
        compute_store(A, grp0);              // waits only A's 12
        A = load_feats(nv2, g2);             // refill
        compute_store(B, g1);                // waits only B's 12
        B = load_feats(nv3, g3);             // refill
        compute_store(A, g2);
        compute_store(B, g3);
    } else {
        // ---- generic fallback (not taken in bench): simple serial loop ----
        for (unsigned grp = grp0; grp < nGroups; grp += stride) {
            const int nv = nodes[grp * 16u + (unsigned)m];
            Feats F = load_feats(nv, grp);
            compute_store(F, grp);
        }
    }
}

extern "C" void kernel_launch(void* const* d_in, const int* in_sizes, int n_in,
                              void* d_out, int out_size, void* d_ws, size_t ws_size,
                              hipStream_t stream) {
    const int*   nodes = (const int*)  d_in[0];
    const float* W     = (const float*)d_in[1];
    const float* L1    = (const float*)d_in[2];
    const float* L2    = (const float*)d_in[3];
    const float* AW    = (const float*)d_in[4];
    const float* AB    = (const float*)d_in[5];
    const float* BW    = (const float*)d_in[6];
    const float* BB    = (const float*)d_in[7];
    const float* GW    = (const float*)d_in[8];
    const float* GB    = (const float*)d_in[9];
    float* out = (float*)d_out;
    const int nrows = in_sizes[0];  // B = 524288

    // 2048 blocks x 4 waves = 8192 persistent waves, exactly 4 groups each
    hipLaunchKernelGGL(encoder_mfma, dim3(2048), dim3(256), 0, stream,
                       nodes, W, L1, L2, AW, AB, BW, BB, GW, GB, out, nrows);
}